// Round 10
// baseline (252.240 us; speedup 1.0000x reference)
//
#include <hip/hip_runtime.h>
#include <math.h>

#define N 1024
#define T 1024           // scan blocks: 16 waves
#define TF 512           // final block: 8 waves, 2 elements/thread
#define HALF 512
#define PHASE_CAP 10
#define SWITCH 56        // run ONE in-block Boruvka phase when comps in (56,~80]:
                         // post-phase comps <= ceil(pre/2) <= 40 < 56 => cannot retrigger.
                         // Trades ~30-36us of VALU-dense phase for ~45us of serial Prim steps.

typedef float v2f __attribute__((ext_vector_type(2)));
typedef unsigned long long ull;

#define INF64 0xFFFFFFFFFFFFFFFFull
#define INF32 0xFFFFFFFFu

__device__ __forceinline__ unsigned umin32(unsigned a, unsigned b) { return a < b ? a : b; }
__device__ __forceinline__ unsigned umax32(unsigned a, unsigned b) { return a > b ? a : b; }
__device__ __forceinline__ int imin32(int a, int b) { return a < b ? a : b; }

// Root walk with 2-cycle detection (keys globally distinct => cycles are exactly
// mutual pairs; root = min of the pair). Safe under concurrent parent[x] <- root(x).
__device__ __forceinline__ unsigned walk_root(const unsigned* parent, unsigned x) {
    unsigned prev = x, cur = parent[x];
    while (cur != prev) {
        unsigned nxt = parent[cur];
        if (nxt == prev) { cur = umin32(cur, prev); break; }
        prev = cur; cur = nxt;
    }
    return cur;
}

// DPP row_shr min step (row = 16 lanes), identity = 0xFFFFFFFF
#define DPP_MIN_SHR(v, sh)                                                                   \
    do {                                                                                     \
        unsigned _t = (unsigned)__builtin_amdgcn_update_dpp(                                 \
            (int)0xFFFFFFFF, (int)(v), 0x110 | (sh), 0xF, 0xF, false);                       \
        (v) = umin32((v), _t);                                                               \
    } while (0)

// ---------- phase-1 scan: 256 blocks = (cloud, node-half). r8-exact. ----------
__global__ __launch_bounds__(T) void scan1_kernel(const float* __restrict__ gts,
                                                  const float* __restrict__ preds,
                                                  unsigned* __restrict__ bests1) {
    __shared__ float4 p4[N];
    __shared__ unsigned pb8[8][HALF];
    const int t = threadIdx.x;
    const int cloud = blockIdx.x >> 1;
    const int nh = blockIdx.x & 1;
    const float* __restrict__ src = (cloud < 64 ? gts : preds) + (size_t)(cloud & 63) * N * 3;

    {
        float* stg = (float*)&pb8[0][0];
        if (t < 768) ((float4*)stg)[t] = ((const float4*)src)[t];
        __syncthreads();
        p4[t] = make_float4(stg[3 * t], stg[3 * t + 1], stg[3 * t + 2], 0.0f);
        __syncthreads();
    }

    const int q = t & 127;
    const int s = t >> 7;
    const int jbase = s << 7;
    const int n0 = nh * HALF + q;
    const int n1 = n0 + 128, n2 = n0 + 256, n3 = n0 + 384;
    const float4 a0 = p4[n0], a1 = p4[n1], a2 = p4[n2], a3 = p4[n3];
    const v2f axA = (v2f){a0.x, a1.x}, ayA = (v2f){a0.y, a1.y}, azA = (v2f){a0.z, a1.z};
    const v2f axB = (v2f){a2.x, a3.x}, ayB = (v2f){a2.y, a3.y}, azB = (v2f){a2.z, a3.z};
    unsigned b0 = INF32, b1 = INF32, b2 = INF32, b3 = INF32;
    #pragma unroll 4
    for (int jj = 0; jj < 128; jj += 2) {
        const int j = jbase + jj;
        const float4 qa = p4[j];
        const float4 qb = p4[j + 1];
        #define STEP1(QQ, JV)                                                           \
        {                                                                               \
            const v2f sxv = (v2f){QQ.x, QQ.x}, syv = (v2f){QQ.y, QQ.y},                 \
                      szv = (v2f){QQ.z, QQ.z};                                          \
            v2f dxA = axA - sxv, dyA = ayA - syv, dzA = azA - szv;                      \
            v2f eA = dxA * dxA;                                                         \
            eA = __builtin_elementwise_fma(dyA, dyA, eA);                               \
            eA = __builtin_elementwise_fma(dzA, dzA, eA);                               \
            v2f dxB = axB - sxv, dyB = ayB - syv, dzB = azB - szv;                      \
            v2f eB = dxB * dxB;                                                         \
            eB = __builtin_elementwise_fma(dyB, dyB, eB);                               \
            eB = __builtin_elementwise_fma(dzB, dzB, eB);                               \
            unsigned kk;                                                                \
            kk = (__float_as_uint(eA.x) & 0xFFFFF800u) | (unsigned)(JV);                \
            b0 = umin32(b0, ((JV) == n0) ? INF32 : kk);                                 \
            kk = (__float_as_uint(eA.y) & 0xFFFFF800u) | (unsigned)(JV);                \
            b1 = umin32(b1, ((JV) == n1) ? INF32 : kk);                                 \
            kk = (__float_as_uint(eB.x) & 0xFFFFF800u) | (unsigned)(JV);                \
            b2 = umin32(b2, ((JV) == n2) ? INF32 : kk);                                 \
            kk = (__float_as_uint(eB.y) & 0xFFFFF800u) | (unsigned)(JV);                \
            b3 = umin32(b3, ((JV) == n3) ? INF32 : kk);                                 \
        }
        STEP1(qa, j)
        STEP1(qb, j + 1)
        #undef STEP1
    }
    pb8[s][q] = b0; pb8[s][q + 128] = b1; pb8[s][q + 256] = b2; pb8[s][q + 384] = b3;
    __syncthreads();
    if (t < HALF) {
        unsigned best = umin32(umin32(pb8[0][t], pb8[1][t]), umin32(pb8[2][t], pb8[3][t]));
        best = umin32(best, umin32(umin32(pb8[4][t], pb8[5][t]), umin32(pb8[6][t], pb8[7][t])));
        bests1[(size_t)cloud * N + nh * HALF + t] = best;
    }
}

// ---------- phase-2 scan: r8-exact ----------
__global__ __launch_bounds__(T) void scan2_kernel(const float* __restrict__ gts,
                                                  const float* __restrict__ preds,
                                                  const unsigned* __restrict__ bests1,
                                                  unsigned* __restrict__ bests2) {
    __shared__ float4 p4[N];
    __shared__ unsigned cw[N];
    __shared__ unsigned parent[N];
    __shared__ unsigned pb8[8][HALF];
    const int t = threadIdx.x;
    const int cloud = blockIdx.x >> 1;
    const int nh = blockIdx.x & 1;
    const float* __restrict__ src = (cloud < 64 ? gts : preds) + (size_t)(cloud & 63) * N * 3;

    {
        float* stg = (float*)&pb8[0][0];
        if (t < 768) ((float4*)stg)[t] = ((const float4*)src)[t];
        __syncthreads();
        p4[t] = make_float4(stg[3 * t], stg[3 * t + 1], stg[3 * t + 2], 0.0f);
    }
    parent[t] = bests1[(size_t)cloud * N + t] & 0x3FFu;
    __syncthreads();
    {
        unsigned r = walk_root(parent, (unsigned)t);
        parent[t] = r;
        cw[t] = r;
    }
    __syncthreads();

    const int q = t & 127;
    const int s = t >> 7;
    const int jbase = s << 7;
    const int n0 = nh * HALF + q;
    const int n1 = n0 + 128, n2 = n0 + 256, n3 = n0 + 384;
    const unsigned c0 = cw[n0], c1 = cw[n1], c2 = cw[n2], c3 = cw[n3];
    const float4 a0 = p4[n0], a1 = p4[n1], a2 = p4[n2], a3 = p4[n3];
    const v2f axA = (v2f){a0.x, a1.x}, ayA = (v2f){a0.y, a1.y}, azA = (v2f){a0.z, a1.z};
    const v2f axB = (v2f){a2.x, a3.x}, ayB = (v2f){a2.y, a3.y}, azB = (v2f){a2.z, a3.z};
    unsigned b0 = INF32, b1 = INF32, b2 = INF32, b3 = INF32;
    #pragma unroll 4
    for (int jj = 0; jj < 128; jj += 2) {
        const int j = jbase + jj;
        const float4 qa = p4[j];
        const float4 qb = p4[j + 1];
        uint2 cj = *(const uint2*)&cw[j];
        #define STEP2(QQ, CJ, JV)                                                       \
        {                                                                               \
            const v2f sxv = (v2f){QQ.x, QQ.x}, syv = (v2f){QQ.y, QQ.y},                 \
                      szv = (v2f){QQ.z, QQ.z};                                          \
            v2f dxA = axA - sxv, dyA = ayA - syv, dzA = azA - szv;                      \
            v2f eA = dxA * dxA;                                                         \
            eA = __builtin_elementwise_fma(dyA, dyA, eA);                               \
            eA = __builtin_elementwise_fma(dzA, dzA, eA);                               \
            v2f dxB = axB - sxv, dyB = ayB - syv, dzB = azB - szv;                      \
            v2f eB = dxB * dxB;                                                         \
            eB = __builtin_elementwise_fma(dyB, dyB, eB);                               \
            eB = __builtin_elementwise_fma(dzB, dzB, eB);                               \
            unsigned kk;                                                                \
            kk = (__float_as_uint(eA.x) & 0xFFFFF800u) | (unsigned)(JV);                \
            b0 = umin32(b0, ((CJ) == c0) ? INF32 : kk);                                 \
            kk = (__float_as_uint(eA.y) & 0xFFFFF800u) | (unsigned)(JV);                \
            b1 = umin32(b1, ((CJ) == c1) ? INF32 : kk);                                 \
            kk = (__float_as_uint(eB.x) & 0xFFFFF800u) | (unsigned)(JV);                \
            b2 = umin32(b2, ((CJ) == c2) ? INF32 : kk);                                 \
            kk = (__float_as_uint(eB.y) & 0xFFFFF800u) | (unsigned)(JV);                \
            b3 = umin32(b3, ((CJ) == c3) ? INF32 : kk);                                 \
        }
        STEP2(qa, cj.x, j)
        STEP2(qb, cj.y, j + 1)
        #undef STEP2
    }
    pb8[s][q] = b0; pb8[s][q + 128] = b1; pb8[s][q + 256] = b2; pb8[s][q + 384] = b3;
    __syncthreads();
    if (t < HALF) {
        unsigned best = umin32(umin32(pb8[0][t], pb8[1][t]), umin32(pb8[2][t], pb8[3][t]));
        best = umin32(best, umin32(umin32(pb8[4][t], pb8[5][t]), umin32(pb8[6][t], pb8[7][t])));
        bests2[(size_t)cloud * N + nh * HALF + t] = best;
    }
}

// ---------- final: 512 threads, 2 elements/thread (e0=t, e1=t+512) ----------
// Also zeroes out[] (block 0) so the memset dispatch is unnecessary: final
// precedes diff_kernel in stream order.
__global__ __launch_bounds__(TF) void final_kernel(const float* __restrict__ gts,
                                                   const float* __restrict__ preds,
                                                   float* __restrict__ ws,
                                                   const unsigned* __restrict__ bests1,
                                                   const unsigned* __restrict__ bests2,
                                                   int nPre,
                                                   float* __restrict__ out) {
    __shared__ float4 pts[N];
    __shared__ float4 spts[N];
    __shared__ unsigned comp[N];
    __shared__ ull bestComp[N];
    __shared__ unsigned parent[N];
    __shared__ __align__(16) unsigned pb[2][N];
    __shared__ float deaths[N];
    __shared__ unsigned wsum[16];
    __shared__ int deathCount;

    const int t = threadIdx.x;
    const int tb = t + HALF;             // second element
    const int blk = blockIdx.x;
    const float* __restrict__ src = (blk < 64 ? gts : preds) + (size_t)(blk & 63) * N * 3;

    if (blk == 0 && t == 0) out[0] = 0.0f;   // replaces hipMemsetAsync (diff runs after)

    // ---- stage + init ----
    {
        float* stg = (float*)&spts[0];
        for (int i = t; i < 768; i += TF) ((float4*)stg)[i] = ((const float4*)src)[i];
        __syncthreads();
        #pragma unroll
        for (int e = t; e < N; e += TF) {
            float x = stg[3 * e], y = stg[3 * e + 1], z = stg[3 * e + 2];
            pts[e] = make_float4(x, y, z, __uint_as_float((unsigned)e));
            comp[e] = (unsigned)e;
            parent[e] = (unsigned)e;
            deaths[e] = 0.0f;
            bestComp[e] = INF64;
        }
    }
    if (t == 0) deathCount = 0;
    __syncthreads();

    // ---- merge phase 1 from bests1 ----
    if (nPre >= 1) {
        unsigned bA = bests1[(size_t)blk * N + t];
        unsigned bB = bests1[(size_t)blk * N + tb];
        unsigned jA = bA & 0x3FFu, eAb = bA & 0xFFFFF800u;
        unsigned jB = bB & 0x3FFu, eBb = bB & 0xFFFFF800u;
        parent[t] = jA;
        parent[tb] = jB;
        __syncthreads();
        {
            unsigned gpA = parent[jA];
            bool recA = !(gpA == (unsigned)t) || ((unsigned)t < jA);
            float dvalA = recA ? sqrtf(__uint_as_float(eAb) + 1e-12f) : 0.0f;
            unsigned gpB = parent[jB];
            bool recB = !(gpB == (unsigned)tb) || ((unsigned)tb < jB);
            float dvalB = recB ? sqrtf(__uint_as_float(eBb) + 1e-12f) : 0.0f;
            ull mA = __ballot(recA), mB = __ballot(recB);
            int cntA = __popcll(mA);
            int cnt = cntA + __popcll(mB);
            int base = 0;
            if ((t & 63) == 0 && cnt) base = atomicAdd(&deathCount, cnt);
            base = __shfl(base, 0, 64);
            ull below = (1ull << (t & 63)) - 1ull;
            if (recA) { int idx = base + __popcll(mA & below); if (idx < N - 1) deaths[idx] = dvalA; }
            if (recB) { int idx = base + cntA + __popcll(mB & below); if (idx < N - 1) deaths[idx] = dvalB; }
        }
        __syncthreads();
        {
            unsigned r = walk_root(parent, (unsigned)t);
            parent[t] = r; comp[t] = r; pts[t].w = __uint_as_float(r);
            unsigned r2 = walk_root(parent, (unsigned)tb);
            parent[tb] = r2; comp[tb] = r2; pts[tb].w = __uint_as_float(r2);
        }
        __syncthreads();
    }

    // ---- merge phase 2 from bests2 ----
    if (nPre >= 2) {
        {
            unsigned b2 = bests2[(size_t)blk * N + t];
            if (b2 != INF32) {
                unsigned j2 = b2 & 0x3FFu, e2 = b2 & 0xFFFFF800u;
                unsigned mn = umin32((unsigned)t, j2), mx = umax32((unsigned)t, j2);
                atomicMin(&bestComp[comp[t]], ((ull)e2 << 20) | (ull)((mn << 10) | mx));
            }
            b2 = bests2[(size_t)blk * N + tb];
            if (b2 != INF32) {
                unsigned j2 = b2 & 0x3FFu, e2 = b2 & 0xFFFFF800u;
                unsigned mn = umin32((unsigned)tb, j2), mx = umax32((unsigned)tb, j2);
                atomicMin(&bestComp[comp[tb]], ((ull)e2 << 20) | (ull)((mn << 10) | mx));
            }
        }
        __syncthreads();
        const bool isRootA = (parent[t] == (unsigned)t);
        const bool isRootB = (parent[tb] == (unsigned)tb);
        {
            ull bc = bestComp[t];
            if (isRootA && bc != INF64) {
                unsigned mn = (unsigned)((bc >> 10) & 0x3FFu), mx = (unsigned)(bc & 0x3FFu);
                unsigned cm = comp[mn];
                parent[t] = (cm == (unsigned)t) ? comp[mx] : cm;
            }
            bc = bestComp[tb];
            if (isRootB && bc != INF64) {
                unsigned mn = (unsigned)((bc >> 10) & 0x3FFu), mx = (unsigned)(bc & 0x3FFu);
                unsigned cm = comp[mn];
                parent[tb] = (cm == (unsigned)tb) ? comp[mx] : cm;
            }
        }
        __syncthreads();
        {
            bool recA = false, recB = false;
            float dvalA = 0.0f, dvalB = 0.0f;
            unsigned p = parent[t];
            if (isRootA && p != (unsigned)t) {
                unsigned gp = parent[p];
                recA = !(gp == (unsigned)t) || ((unsigned)t < p);
                if (recA) dvalA = sqrtf(__uint_as_float((unsigned)(bestComp[t] >> 20)) + 1e-12f);
            }
            p = parent[tb];
            if (isRootB && p != (unsigned)tb) {
                unsigned gp = parent[p];
                recB = !(gp == (unsigned)tb) || ((unsigned)tb < p);
                if (recB) dvalB = sqrtf(__uint_as_float((unsigned)(bestComp[tb] >> 20)) + 1e-12f);
            }
            ull mA = __ballot(recA), mB = __ballot(recB);
            int cntA = __popcll(mA);
            int cnt = cntA + __popcll(mB);
            int base = 0;
            if ((t & 63) == 0 && cnt) base = atomicAdd(&deathCount, cnt);
            base = __shfl(base, 0, 64);
            ull below = (1ull << (t & 63)) - 1ull;
            if (recA) { int idx = base + __popcll(mA & below); if (idx < N - 1) deaths[idx] = dvalA; }
            if (recB) { int idx = base + cntA + __popcll(mB & below); if (idx < N - 1) deaths[idx] = dvalB; }
        }
        __syncthreads();
        {
            unsigned r = walk_root(parent, (unsigned)t);
            parent[t] = r;
            unsigned nc = walk_root(parent, comp[t]);
            comp[t] = nc; pts[t].w = __uint_as_float(nc); bestComp[t] = INF64;
            r = walk_root(parent, (unsigned)tb);
            parent[tb] = r;
            nc = walk_root(parent, comp[tb]);
            comp[tb] = nc; pts[tb].w = __uint_as_float(nc); bestComp[tb] = INF64;
        }
        __syncthreads();
    }

    // ---- in-block Boruvka phases (one phase expected when comps in (56,~80]) ----
    {
        float4 pA = pts[t], pB = pts[tb];
        const v2f pxv = (v2f){pA.x, pB.x};
        const v2f pyv = (v2f){pA.y, pB.y};
        const v2f pzv = (v2f){pA.z, pB.z};
        int phase = nPre;
        while (N - deathCount > (nPre ? SWITCH : 1) && phase < PHASE_CAP) {
            const unsigned c0 = comp[t], c1 = comp[tb];
            unsigned best0 = INF32, best1 = INF32;
            #pragma unroll 8
            for (int j = 0; j < N; ++j) {
                float4 pj = pts[j];
                unsigned cj = __float_as_uint(pj.w);
                v2f dx = pxv - (v2f){pj.x, pj.x};
                v2f dy = pyv - (v2f){pj.y, pj.y};
                v2f dz = pzv - (v2f){pj.z, pj.z};
                v2f e = dx * dx;
                e = __builtin_elementwise_fma(dy, dy, e);
                e = __builtin_elementwise_fma(dz, dz, e);
                unsigned k0 = (__float_as_uint(e.x) & 0xFFFFF800u) | (unsigned)j;
                unsigned k1 = (__float_as_uint(e.y) & 0xFFFFF800u) | (unsigned)j;
                k0 = (cj == c0) ? INF32 : k0;
                k1 = (cj == c1) ? INF32 : k1;
                best0 = umin32(best0, k0);
                best1 = umin32(best1, k1);
            }
            if (best0 != INF32) {
                unsigned j = best0 & 0x3FFu, e = best0 & 0xFFFFF800u;
                unsigned mn = umin32((unsigned)t, j), mx = umax32((unsigned)t, j);
                ull key = ((ull)e << 20) | (ull)((mn << 10) | mx);
                if (phase == 0) bestComp[t] = key;
                else atomicMin(&bestComp[comp[t]], key);
            }
            if (best1 != INF32) {
                unsigned j = best1 & 0x3FFu, e = best1 & 0xFFFFF800u;
                unsigned mn = umin32((unsigned)tb, j), mx = umax32((unsigned)tb, j);
                ull key = ((ull)e << 20) | (ull)((mn << 10) | mx);
                if (phase == 0) bestComp[tb] = key;
                else atomicMin(&bestComp[comp[tb]], key);
            }
            __syncthreads();
            const bool isRootA = (parent[t] == (unsigned)t);
            const bool isRootB = (parent[tb] == (unsigned)tb);
            {
                ull bc = bestComp[t];
                if (isRootA && bc != INF64) {
                    unsigned mn = (unsigned)((bc >> 10) & 0x3FFu), mx = (unsigned)(bc & 0x3FFu);
                    unsigned cm = comp[mn];
                    parent[t] = (cm == (unsigned)t) ? comp[mx] : cm;
                }
                bc = bestComp[tb];
                if (isRootB && bc != INF64) {
                    unsigned mn = (unsigned)((bc >> 10) & 0x3FFu), mx = (unsigned)(bc & 0x3FFu);
                    unsigned cm = comp[mn];
                    parent[tb] = (cm == (unsigned)tb) ? comp[mx] : cm;
                }
            }
            __syncthreads();
            {
                bool recA = false, recB = false;
                float dvalA = 0.0f, dvalB = 0.0f;
                unsigned p = parent[t];
                if (isRootA && p != (unsigned)t) {
                    unsigned gp = parent[p];
                    recA = !(gp == (unsigned)t) || ((unsigned)t < p);
                    if (recA) dvalA = sqrtf(__uint_as_float((unsigned)(bestComp[t] >> 20)) + 1e-12f);
                }
                p = parent[tb];
                if (isRootB && p != (unsigned)tb) {
                    unsigned gp = parent[p];
                    recB = !(gp == (unsigned)tb) || ((unsigned)tb < p);
                    if (recB) dvalB = sqrtf(__uint_as_float((unsigned)(bestComp[tb] >> 20)) + 1e-12f);
                }
                ull mA = __ballot(recA), mB = __ballot(recB);
                int cntA = __popcll(mA);
                int cnt = cntA + __popcll(mB);
                int base = 0;
                if ((t & 63) == 0 && cnt) base = atomicAdd(&deathCount, cnt);
                base = __shfl(base, 0, 64);
                ull below = (1ull << (t & 63)) - 1ull;
                if (recA) { int idx = base + __popcll(mA & below); if (idx < N - 1) deaths[idx] = dvalA; }
                if (recB) { int idx = base + cntA + __popcll(mB & below); if (idx < N - 1) deaths[idx] = dvalB; }
            }
            __syncthreads();
            {
                unsigned r = walk_root(parent, (unsigned)t);
                parent[t] = r;
                unsigned nc = walk_root(parent, comp[t]);
                comp[t] = nc; pts[t].w = __uint_as_float(nc); bestComp[t] = INF64;
                r = walk_root(parent, (unsigned)tb);
                parent[tb] = r;
                nc = walk_root(parent, comp[tb]);
                comp[tb] = nc; pts[tb].w = __uint_as_float(nc); bestComp[tb] = INF64;
            }
            __syncthreads();
            ++phase;
        }
    }

    // ================= Contracted Prim on remaining comps =================
    const int dcbase = deathCount;
    const int comps = N - dcbase;
    if (comps > 1) {
        unsigned* scomp = &pb[0][0];
        unsigned* hist = &pb[1][0];
        unsigned* wavemin = &pb[1][0];
        uint2* segs = (uint2*)&bestComp[0];
        const int lane = t & 63;
        const int wid = t >> 6;          // 0..7

        hist[t] = 0; hist[tb] = 0;
        __syncthreads();
        atomicAdd(&hist[comp[t]], 1u);
        atomicAdd(&hist[comp[tb]], 1u);
        __syncthreads();
        unsigned cA = hist[t], cB = hist[tb];
        unsigned incA = cA, incB = cB;
        #pragma unroll
        for (int d = 1; d < 64; d <<= 1) {
            unsigned uA = __shfl_up(incA, d, 64);
            unsigned uB = __shfl_up(incB, d, 64);
            if (lane >= d) { incA += uA; incB += uB; }
        }
        if (lane == 63) { wsum[wid] = incA; wsum[8 + wid] = incB; }
        __syncthreads();
        unsigned wofA = 0, totA = 0, wofB = 0;
        for (int i = 0; i < 8; ++i) {
            unsigned w = wsum[i];
            if (i < wid) wofA += w;
            totA += w;
        }
        for (int i = 0; i < wid; ++i) wofB += wsum[8 + i];
        unsigned exclA = wofA + incA - cA;               // bins 0..511
        unsigned exclB = totA + wofB + incB - cB;        // bins 512..1023
        if (cA) { segs[t].x = exclA; segs[t].y = exclA + cA; }
        if (cB) { segs[tb].x = exclB; segs[tb].y = exclB + cB; }
        __syncthreads();
        hist[t] = exclA; hist[tb] = exclB;
        __syncthreads();
        {
            unsigned pos = atomicAdd(&hist[comp[t]], 1u);
            spts[pos] = pts[t]; scomp[pos] = comp[t];
            pos = atomicAdd(&hist[comp[tb]], 1u);
            spts[pos] = pts[tb]; scomp[pos] = comp[tb];
        }
        __syncthreads();

        unsigned c_cur = comp[0];
        v2f pxv2 = (v2f){0.f, 0.f}, pyv2 = pxv2, pzv2 = pxv2;
        unsigned myc0 = 0, myc1 = 0, md0 = INF32, md1 = INF32;
        {
            float4 q0 = spts[t], q1 = spts[tb];
            myc0 = scomp[t];
            myc1 = scomp[tb];
            pxv2 = (v2f){q0.x, q1.x};
            pyv2 = (v2f){q0.y, q1.y};
            pzv2 = (v2f){q0.z, q1.z};
            if (myc0 == c_cur) pxv2.x = INFINITY;
            if (myc1 == c_cur) pxv2.y = INFINITY;
        }

        for (int step = 0; step < comps - 1; ++step) {
            {
                uint2 sg = segs[c_cur];
                const int jb = (int)sg.x, je = (int)sg.y, jl = je - 1;
                for (int base = jb; base < je; base += 4) {
                    float4 q0 = spts[base];
                    float4 q1 = spts[imin32(base + 1, jl)];
                    float4 q2 = spts[imin32(base + 2, jl)];
                    float4 q3 = spts[imin32(base + 3, jl)];
                    #define RELAX(qq)                                                        \
                        {                                                                    \
                            v2f dx = pxv2 - (v2f){qq.x, qq.x};                               \
                            v2f dy = pyv2 - (v2f){qq.y, qq.y};                               \
                            v2f dz = pzv2 - (v2f){qq.z, qq.z};                               \
                            v2f e = dx * dx;                                                 \
                            e = __builtin_elementwise_fma(dy, dy, e);                        \
                            e = __builtin_elementwise_fma(dz, dz, e);                        \
                            md0 = umin32(md0, (__float_as_uint(e.x) & 0xFFFFFC00u) | myc0);  \
                            md1 = umin32(md1, (__float_as_uint(e.y) & 0xFFFFFC00u) | myc1);  \
                        }
                    RELAX(q0) RELAX(q1) RELAX(q2) RELAX(q3)
                    #undef RELAX
                }
                unsigned v = umin32(md0, md1);
                DPP_MIN_SHR(v, 1);
                DPP_MIN_SHR(v, 2);
                DPP_MIN_SHR(v, 4);
                DPP_MIN_SHR(v, 8);
                unsigned r0 = (unsigned)__builtin_amdgcn_readlane((int)v, 15);
                unsigned r1 = (unsigned)__builtin_amdgcn_readlane((int)v, 31);
                unsigned r2 = (unsigned)__builtin_amdgcn_readlane((int)v, 47);
                unsigned r3 = (unsigned)__builtin_amdgcn_readlane((int)v, 63);
                if (lane == 0)
                    wavemin[(step & 1) * 8 + wid] = umin32(umin32(r0, r1), umin32(r2, r3));
            }
            __syncthreads();                     // 8-wave barrier
            {
                const uint4* wmv = (const uint4*)(wavemin + (step & 1) * 8);
                uint4 u0 = wmv[0], u1 = wmv[1];
                unsigned m0 = umin32(umin32(u0.x, u0.y), umin32(u0.z, u0.w));
                unsigned m1 = umin32(umin32(u1.x, u1.y), umin32(u1.z, u1.w));
                unsigned G = umin32(m0, m1);
                c_cur = G & 0x3FFu;
                if (t == 0)
                    deaths[dcbase + step] = sqrtf(__uint_as_float(G & 0xFFFFFC00u) + 1e-12f);
                if (myc0 == c_cur) { pxv2.x = INFINITY; md0 = INF32; }
                if (myc1 == c_cur) { pxv2.y = INFINITY; md1 = INF32; }
            }
        }
    }

    // ---- hybrid bitonic sort, 2 register elements/thread ----
    {
        float v0 = deaths[t], v1 = deaths[tb];
        if (t == TF - 1) v1 = INFINITY;          // element N-1 pad
        #pragma unroll
        for (int k = 2; k <= N; k <<= 1) {
            #pragma unroll
            for (int j = k >> 1; j > 0; j >>= 1) {
                const bool up0 = ((t & k) == 0);
                const bool up1 = ((tb & k) == 0);
                float u0, u1;
                if (j == 512) {
                    u0 = v1; u1 = v0;
                } else if (j >= 64) {
                    deaths[t] = v0; deaths[tb] = v1;
                    __syncthreads();
                    u0 = deaths[t ^ j];
                    u1 = deaths[tb ^ j];
                    __syncthreads();
                } else {
                    u0 = __shfl_xor(v0, j, 64);
                    u1 = __shfl_xor(v1, j, 64);
                }
                v0 = (((t & j) == 0) == up0) ? fminf(v0, u0) : fmaxf(v0, u0);
                v1 = (((tb & j) == 0) == up1) ? fminf(v1, u1) : fmaxf(v1, u1);
            }
        }
        float* dst = ws + (size_t)blk * N;
        dst[t] = v0;
        dst[tb] = (tb < N - 1) ? v1 : 0.0f;
    }
}

// Fused diff: 64 blocks; per-batch |a-b| sum -> atomicAdd into out (zeroed by final).
__global__ __launch_bounds__(256) void diff_kernel(const float* __restrict__ ws,
                                                   float* __restrict__ out) {
    __shared__ float red[4];
    const int t = threadIdx.x;
    const int b = blockIdx.x;
    const float* a = ws + (size_t)b * N;
    const float* c = ws + (size_t)(64 + b) * N;
    float sum = 0.0f;
    for (int i = t; i < N; i += 256)
        sum += fabsf(a[i] - c[i]);
    #pragma unroll
    for (int off = 32; off > 0; off >>= 1)
        sum += __shfl_down(sum, off, 64);
    if ((t & 63) == 0) red[t >> 6] = sum;
    __syncthreads();
    if (t == 0)
        atomicAdd(out, (red[0] + red[1] + red[2] + red[3]) * (1.0f / 64.0f));
}

extern "C" void kernel_launch(void* const* d_in, const int* in_sizes, int n_in,
                              void* d_out, int out_size, void* d_ws, size_t ws_size,
                              hipStream_t stream) {
    const float* gts = (const float*)d_in[0];
    const float* preds = (const float*)d_in[1];
    float* ws = (float*)d_ws;                     // sorted deaths live at ws[0 .. 128*N)
    unsigned* bests1 = (unsigned*)d_ws;           // 512 KiB (overwritten by sorted deaths)
    unsigned* bests2 = bests1 + 128 * N;          // 512 KiB
    const bool big = ws_size >= (size_t)(2u * 128u * N * 4u);

    if (big) {
        hipLaunchKernelGGL(scan1_kernel, dim3(256), dim3(T), 0, stream, gts, preds, bests1);
        hipLaunchKernelGGL(scan2_kernel, dim3(256), dim3(T), 0, stream, gts, preds, bests1, bests2);
        hipLaunchKernelGGL(final_kernel, dim3(128), dim3(TF), 0, stream,
                           gts, preds, ws, bests1, bests2, 2, (float*)d_out);
    } else {
        hipLaunchKernelGGL(final_kernel, dim3(128), dim3(TF), 0, stream,
                           gts, preds, ws, (const unsigned*)nullptr, (const unsigned*)nullptr, 0,
                           (float*)d_out);
    }
    hipLaunchKernelGGL(diff_kernel, dim3(64), dim3(256), 0, stream, ws, (float*)d_out);
}

// Round 11
// 213.263 us; speedup vs baseline: 1.1828x; 1.1828x over previous
//
#include <hip/hip_runtime.h>
#include <math.h>

#define N 1024
#define T 1024           // scan blocks: 16 waves
#define TF 512           // final block: 8 waves, 2 elements/thread
#define HALF 512
#define PHASE_CAP 10
#define SWITCH 80        // Boruvka fallback only if comps > 80 (never on this data).
                         // r10 measured: one TF=512 phase costs ~80us (2048 pair-evals/thread,
                         // 8 waves) vs ~35us of Prim steps saved -> never trade at comps<=80.

typedef float v2f __attribute__((ext_vector_type(2)));
typedef unsigned long long ull;

#define INF64 0xFFFFFFFFFFFFFFFFull
#define INF32 0xFFFFFFFFu

__device__ __forceinline__ unsigned umin32(unsigned a, unsigned b) { return a < b ? a : b; }
__device__ __forceinline__ unsigned umax32(unsigned a, unsigned b) { return a > b ? a : b; }
__device__ __forceinline__ int imin32(int a, int b) { return a < b ? a : b; }

// Root walk with 2-cycle detection (keys globally distinct => cycles are exactly
// mutual pairs; root = min of the pair). Safe under concurrent parent[x] <- root(x).
__device__ __forceinline__ unsigned walk_root(const unsigned* parent, unsigned x) {
    unsigned prev = x, cur = parent[x];
    while (cur != prev) {
        unsigned nxt = parent[cur];
        if (nxt == prev) { cur = umin32(cur, prev); break; }
        prev = cur; cur = nxt;
    }
    return cur;
}

// DPP row_shr min step (row = 16 lanes), identity = 0xFFFFFFFF
#define DPP_MIN_SHR(v, sh)                                                                   \
    do {                                                                                     \
        unsigned _t = (unsigned)__builtin_amdgcn_update_dpp(                                 \
            (int)0xFFFFFFFF, (int)(v), 0x110 | (sh), 0xF, 0xF, false);                       \
        (v) = umin32((v), _t);                                                               \
    } while (0)

// ---------- phase-1 scan: 256 blocks = (cloud, node-half). r8-exact. ----------
__global__ __launch_bounds__(T) void scan1_kernel(const float* __restrict__ gts,
                                                  const float* __restrict__ preds,
                                                  unsigned* __restrict__ bests1) {
    __shared__ float4 p4[N];
    __shared__ unsigned pb8[8][HALF];
    const int t = threadIdx.x;
    const int cloud = blockIdx.x >> 1;
    const int nh = blockIdx.x & 1;
    const float* __restrict__ src = (cloud < 64 ? gts : preds) + (size_t)(cloud & 63) * N * 3;

    {
        float* stg = (float*)&pb8[0][0];
        if (t < 768) ((float4*)stg)[t] = ((const float4*)src)[t];
        __syncthreads();
        p4[t] = make_float4(stg[3 * t], stg[3 * t + 1], stg[3 * t + 2], 0.0f);
        __syncthreads();
    }

    const int q = t & 127;
    const int s = t >> 7;
    const int jbase = s << 7;
    const int n0 = nh * HALF + q;
    const int n1 = n0 + 128, n2 = n0 + 256, n3 = n0 + 384;
    const float4 a0 = p4[n0], a1 = p4[n1], a2 = p4[n2], a3 = p4[n3];
    const v2f axA = (v2f){a0.x, a1.x}, ayA = (v2f){a0.y, a1.y}, azA = (v2f){a0.z, a1.z};
    const v2f axB = (v2f){a2.x, a3.x}, ayB = (v2f){a2.y, a3.y}, azB = (v2f){a2.z, a3.z};
    unsigned b0 = INF32, b1 = INF32, b2 = INF32, b3 = INF32;
    #pragma unroll 4
    for (int jj = 0; jj < 128; jj += 2) {
        const int j = jbase + jj;
        const float4 qa = p4[j];
        const float4 qb = p4[j + 1];
        #define STEP1(QQ, JV)                                                           \
        {                                                                               \
            const v2f sxv = (v2f){QQ.x, QQ.x}, syv = (v2f){QQ.y, QQ.y},                 \
                      szv = (v2f){QQ.z, QQ.z};                                          \
            v2f dxA = axA - sxv, dyA = ayA - syv, dzA = azA - szv;                      \
            v2f eA = dxA * dxA;                                                         \
            eA = __builtin_elementwise_fma(dyA, dyA, eA);                               \
            eA = __builtin_elementwise_fma(dzA, dzA, eA);                               \
            v2f dxB = axB - sxv, dyB = ayB - syv, dzB = azB - szv;                      \
            v2f eB = dxB * dxB;                                                         \
            eB = __builtin_elementwise_fma(dyB, dyB, eB);                               \
            eB = __builtin_elementwise_fma(dzB, dzB, eB);                               \
            unsigned kk;                                                                \
            kk = (__float_as_uint(eA.x) & 0xFFFFF800u) | (unsigned)(JV);                \
            b0 = umin32(b0, ((JV) == n0) ? INF32 : kk);                                 \
            kk = (__float_as_uint(eA.y) & 0xFFFFF800u) | (unsigned)(JV);                \
            b1 = umin32(b1, ((JV) == n1) ? INF32 : kk);                                 \
            kk = (__float_as_uint(eB.x) & 0xFFFFF800u) | (unsigned)(JV);                \
            b2 = umin32(b2, ((JV) == n2) ? INF32 : kk);                                 \
            kk = (__float_as_uint(eB.y) & 0xFFFFF800u) | (unsigned)(JV);                \
            b3 = umin32(b3, ((JV) == n3) ? INF32 : kk);                                 \
        }
        STEP1(qa, j)
        STEP1(qb, j + 1)
        #undef STEP1
    }
    pb8[s][q] = b0; pb8[s][q + 128] = b1; pb8[s][q + 256] = b2; pb8[s][q + 384] = b3;
    __syncthreads();
    if (t < HALF) {
        unsigned best = umin32(umin32(pb8[0][t], pb8[1][t]), umin32(pb8[2][t], pb8[3][t]));
        best = umin32(best, umin32(umin32(pb8[4][t], pb8[5][t]), umin32(pb8[6][t], pb8[7][t])));
        bests1[(size_t)cloud * N + nh * HALF + t] = best;
    }
}

// ---------- phase-2 scan: r8-exact ----------
__global__ __launch_bounds__(T) void scan2_kernel(const float* __restrict__ gts,
                                                  const float* __restrict__ preds,
                                                  const unsigned* __restrict__ bests1,
                                                  unsigned* __restrict__ bests2) {
    __shared__ float4 p4[N];
    __shared__ unsigned cw[N];
    __shared__ unsigned parent[N];
    __shared__ unsigned pb8[8][HALF];
    const int t = threadIdx.x;
    const int cloud = blockIdx.x >> 1;
    const int nh = blockIdx.x & 1;
    const float* __restrict__ src = (cloud < 64 ? gts : preds) + (size_t)(cloud & 63) * N * 3;

    {
        float* stg = (float*)&pb8[0][0];
        if (t < 768) ((float4*)stg)[t] = ((const float4*)src)[t];
        __syncthreads();
        p4[t] = make_float4(stg[3 * t], stg[3 * t + 1], stg[3 * t + 2], 0.0f);
    }
    parent[t] = bests1[(size_t)cloud * N + t] & 0x3FFu;
    __syncthreads();
    {
        unsigned r = walk_root(parent, (unsigned)t);
        parent[t] = r;
        cw[t] = r;
    }
    __syncthreads();

    const int q = t & 127;
    const int s = t >> 7;
    const int jbase = s << 7;
    const int n0 = nh * HALF + q;
    const int n1 = n0 + 128, n2 = n0 + 256, n3 = n0 + 384;
    const unsigned c0 = cw[n0], c1 = cw[n1], c2 = cw[n2], c3 = cw[n3];
    const float4 a0 = p4[n0], a1 = p4[n1], a2 = p4[n2], a3 = p4[n3];
    const v2f axA = (v2f){a0.x, a1.x}, ayA = (v2f){a0.y, a1.y}, azA = (v2f){a0.z, a1.z};
    const v2f axB = (v2f){a2.x, a3.x}, ayB = (v2f){a2.y, a3.y}, azB = (v2f){a2.z, a3.z};
    unsigned b0 = INF32, b1 = INF32, b2 = INF32, b3 = INF32;
    #pragma unroll 4
    for (int jj = 0; jj < 128; jj += 2) {
        const int j = jbase + jj;
        const float4 qa = p4[j];
        const float4 qb = p4[j + 1];
        uint2 cj = *(const uint2*)&cw[j];
        #define STEP2(QQ, CJ, JV)                                                       \
        {                                                                               \
            const v2f sxv = (v2f){QQ.x, QQ.x}, syv = (v2f){QQ.y, QQ.y},                 \
                      szv = (v2f){QQ.z, QQ.z};                                          \
            v2f dxA = axA - sxv, dyA = ayA - syv, dzA = azA - szv;                      \
            v2f eA = dxA * dxA;                                                         \
            eA = __builtin_elementwise_fma(dyA, dyA, eA);                               \
            eA = __builtin_elementwise_fma(dzA, dzA, eA);                               \
            v2f dxB = axB - sxv, dyB = ayB - syv, dzB = azB - szv;                      \
            v2f eB = dxB * dxB;                                                         \
            eB = __builtin_elementwise_fma(dyB, dyB, eB);                               \
            eB = __builtin_elementwise_fma(dzB, dzB, eB);                               \
            unsigned kk;                                                                \
            kk = (__float_as_uint(eA.x) & 0xFFFFF800u) | (unsigned)(JV);                \
            b0 = umin32(b0, ((CJ) == c0) ? INF32 : kk);                                 \
            kk = (__float_as_uint(eA.y) & 0xFFFFF800u) | (unsigned)(JV);                \
            b1 = umin32(b1, ((CJ) == c1) ? INF32 : kk);                                 \
            kk = (__float_as_uint(eB.x) & 0xFFFFF800u) | (unsigned)(JV);                \
            b2 = umin32(b2, ((CJ) == c2) ? INF32 : kk);                                 \
            kk = (__float_as_uint(eB.y) & 0xFFFFF800u) | (unsigned)(JV);                \
            b3 = umin32(b3, ((CJ) == c3) ? INF32 : kk);                                 \
        }
        STEP2(qa, cj.x, j)
        STEP2(qb, cj.y, j + 1)
        #undef STEP2
    }
    pb8[s][q] = b0; pb8[s][q + 128] = b1; pb8[s][q + 256] = b2; pb8[s][q + 384] = b3;
    __syncthreads();
    if (t < HALF) {
        unsigned best = umin32(umin32(pb8[0][t], pb8[1][t]), umin32(pb8[2][t], pb8[3][t]));
        best = umin32(best, umin32(umin32(pb8[4][t], pb8[5][t]), umin32(pb8[6][t], pb8[7][t])));
        bests2[(size_t)cloud * N + nh * HALF + t] = best;
    }
}

// ---------- final: 512 threads, 2 elements/thread (e0=t, e1=t+512) ----------
// Zeroes out[] (block 0) so no memset dispatch is needed (diff runs after in-stream).
__global__ __launch_bounds__(TF) void final_kernel(const float* __restrict__ gts,
                                                   const float* __restrict__ preds,
                                                   float* __restrict__ ws,
                                                   const unsigned* __restrict__ bests1,
                                                   const unsigned* __restrict__ bests2,
                                                   int nPre,
                                                   float* __restrict__ out) {
    __shared__ float4 pts[N];
    __shared__ float4 spts[N];
    __shared__ unsigned comp[N];
    __shared__ ull bestComp[N];
    __shared__ unsigned parent[N];
    __shared__ __align__(16) unsigned pb[2][N];
    __shared__ float deaths[N];
    __shared__ unsigned wsum[16];
    __shared__ int deathCount;

    const int t = threadIdx.x;
    const int tb = t + HALF;             // second element
    const int blk = blockIdx.x;
    const float* __restrict__ src = (blk < 64 ? gts : preds) + (size_t)(blk & 63) * N * 3;

    if (blk == 0 && t == 0) out[0] = 0.0f;   // replaces hipMemsetAsync (diff runs after)

    // ---- stage + init ----
    {
        float* stg = (float*)&spts[0];
        for (int i = t; i < 768; i += TF) ((float4*)stg)[i] = ((const float4*)src)[i];
        __syncthreads();
        #pragma unroll
        for (int e = t; e < N; e += TF) {
            float x = stg[3 * e], y = stg[3 * e + 1], z = stg[3 * e + 2];
            pts[e] = make_float4(x, y, z, __uint_as_float((unsigned)e));
            comp[e] = (unsigned)e;
            parent[e] = (unsigned)e;
            deaths[e] = 0.0f;
            bestComp[e] = INF64;
        }
    }
    if (t == 0) deathCount = 0;
    __syncthreads();

    // ---- merge phase 1 from bests1 ----
    if (nPre >= 1) {
        unsigned bA = bests1[(size_t)blk * N + t];
        unsigned bB = bests1[(size_t)blk * N + tb];
        unsigned jA = bA & 0x3FFu, eAb = bA & 0xFFFFF800u;
        unsigned jB = bB & 0x3FFu, eBb = bB & 0xFFFFF800u;
        parent[t] = jA;
        parent[tb] = jB;
        __syncthreads();
        {
            unsigned gpA = parent[jA];
            bool recA = !(gpA == (unsigned)t) || ((unsigned)t < jA);
            float dvalA = recA ? sqrtf(__uint_as_float(eAb) + 1e-12f) : 0.0f;
            unsigned gpB = parent[jB];
            bool recB = !(gpB == (unsigned)tb) || ((unsigned)tb < jB);
            float dvalB = recB ? sqrtf(__uint_as_float(eBb) + 1e-12f) : 0.0f;
            ull mA = __ballot(recA), mB = __ballot(recB);
            int cntA = __popcll(mA);
            int cnt = cntA + __popcll(mB);
            int base = 0;
            if ((t & 63) == 0 && cnt) base = atomicAdd(&deathCount, cnt);
            base = __shfl(base, 0, 64);
            ull below = (1ull << (t & 63)) - 1ull;
            if (recA) { int idx = base + __popcll(mA & below); if (idx < N - 1) deaths[idx] = dvalA; }
            if (recB) { int idx = base + cntA + __popcll(mB & below); if (idx < N - 1) deaths[idx] = dvalB; }
        }
        __syncthreads();
        {
            unsigned r = walk_root(parent, (unsigned)t);
            parent[t] = r; comp[t] = r; pts[t].w = __uint_as_float(r);
            unsigned r2 = walk_root(parent, (unsigned)tb);
            parent[tb] = r2; comp[tb] = r2; pts[tb].w = __uint_as_float(r2);
        }
        __syncthreads();
    }

    // ---- merge phase 2 from bests2 ----
    if (nPre >= 2) {
        {
            unsigned b2 = bests2[(size_t)blk * N + t];
            if (b2 != INF32) {
                unsigned j2 = b2 & 0x3FFu, e2 = b2 & 0xFFFFF800u;
                unsigned mn = umin32((unsigned)t, j2), mx = umax32((unsigned)t, j2);
                atomicMin(&bestComp[comp[t]], ((ull)e2 << 20) | (ull)((mn << 10) | mx));
            }
            b2 = bests2[(size_t)blk * N + tb];
            if (b2 != INF32) {
                unsigned j2 = b2 & 0x3FFu, e2 = b2 & 0xFFFFF800u;
                unsigned mn = umin32((unsigned)tb, j2), mx = umax32((unsigned)tb, j2);
                atomicMin(&bestComp[comp[tb]], ((ull)e2 << 20) | (ull)((mn << 10) | mx));
            }
        }
        __syncthreads();
        const bool isRootA = (parent[t] == (unsigned)t);
        const bool isRootB = (parent[tb] == (unsigned)tb);
        {
            ull bc = bestComp[t];
            if (isRootA && bc != INF64) {
                unsigned mn = (unsigned)((bc >> 10) & 0x3FFu), mx = (unsigned)(bc & 0x3FFu);
                unsigned cm = comp[mn];
                parent[t] = (cm == (unsigned)t) ? comp[mx] : cm;
            }
            bc = bestComp[tb];
            if (isRootB && bc != INF64) {
                unsigned mn = (unsigned)((bc >> 10) & 0x3FFu), mx = (unsigned)(bc & 0x3FFu);
                unsigned cm = comp[mn];
                parent[tb] = (cm == (unsigned)tb) ? comp[mx] : cm;
            }
        }
        __syncthreads();
        {
            bool recA = false, recB = false;
            float dvalA = 0.0f, dvalB = 0.0f;
            unsigned p = parent[t];
            if (isRootA && p != (unsigned)t) {
                unsigned gp = parent[p];
                recA = !(gp == (unsigned)t) || ((unsigned)t < p);
                if (recA) dvalA = sqrtf(__uint_as_float((unsigned)(bestComp[t] >> 20)) + 1e-12f);
            }
            p = parent[tb];
            if (isRootB && p != (unsigned)tb) {
                unsigned gp = parent[p];
                recB = !(gp == (unsigned)tb) || ((unsigned)tb < p);
                if (recB) dvalB = sqrtf(__uint_as_float((unsigned)(bestComp[tb] >> 20)) + 1e-12f);
            }
            ull mA = __ballot(recA), mB = __ballot(recB);
            int cntA = __popcll(mA);
            int cnt = cntA + __popcll(mB);
            int base = 0;
            if ((t & 63) == 0 && cnt) base = atomicAdd(&deathCount, cnt);
            base = __shfl(base, 0, 64);
            ull below = (1ull << (t & 63)) - 1ull;
            if (recA) { int idx = base + __popcll(mA & below); if (idx < N - 1) deaths[idx] = dvalA; }
            if (recB) { int idx = base + cntA + __popcll(mB & below); if (idx < N - 1) deaths[idx] = dvalB; }
        }
        __syncthreads();
        {
            unsigned r = walk_root(parent, (unsigned)t);
            parent[t] = r;
            unsigned nc = walk_root(parent, comp[t]);
            comp[t] = nc; pts[t].w = __uint_as_float(nc); bestComp[t] = INF64;
            r = walk_root(parent, (unsigned)tb);
            parent[tb] = r;
            nc = walk_root(parent, comp[tb]);
            comp[tb] = nc; pts[tb].w = __uint_as_float(nc); bestComp[tb] = INF64;
        }
        __syncthreads();
    }

    // ---- in-block Boruvka phases (fallback; dead at runtime with comps<=80) ----
    {
        float4 pA = pts[t], pB = pts[tb];
        const v2f pxv = (v2f){pA.x, pB.x};
        const v2f pyv = (v2f){pA.y, pB.y};
        const v2f pzv = (v2f){pA.z, pB.z};
        int phase = nPre;
        while (N - deathCount > (nPre ? SWITCH : 1) && phase < PHASE_CAP) {
            const unsigned c0 = comp[t], c1 = comp[tb];
            unsigned best0 = INF32, best1 = INF32;
            #pragma unroll 8
            for (int j = 0; j < N; ++j) {
                float4 pj = pts[j];
                unsigned cj = __float_as_uint(pj.w);
                v2f dx = pxv - (v2f){pj.x, pj.x};
                v2f dy = pyv - (v2f){pj.y, pj.y};
                v2f dz = pzv - (v2f){pj.z, pj.z};
                v2f e = dx * dx;
                e = __builtin_elementwise_fma(dy, dy, e);
                e = __builtin_elementwise_fma(dz, dz, e);
                unsigned k0 = (__float_as_uint(e.x) & 0xFFFFF800u) | (unsigned)j;
                unsigned k1 = (__float_as_uint(e.y) & 0xFFFFF800u) | (unsigned)j;
                k0 = (cj == c0) ? INF32 : k0;
                k1 = (cj == c1) ? INF32 : k1;
                best0 = umin32(best0, k0);
                best1 = umin32(best1, k1);
            }
            if (best0 != INF32) {
                unsigned j = best0 & 0x3FFu, e = best0 & 0xFFFFF800u;
                unsigned mn = umin32((unsigned)t, j), mx = umax32((unsigned)t, j);
                ull key = ((ull)e << 20) | (ull)((mn << 10) | mx);
                if (phase == 0) bestComp[t] = key;
                else atomicMin(&bestComp[comp[t]], key);
            }
            if (best1 != INF32) {
                unsigned j = best1 & 0x3FFu, e = best1 & 0xFFFFF800u;
                unsigned mn = umin32((unsigned)tb, j), mx = umax32((unsigned)tb, j);
                ull key = ((ull)e << 20) | (ull)((mn << 10) | mx);
                if (phase == 0) bestComp[tb] = key;
                else atomicMin(&bestComp[comp[tb]], key);
            }
            __syncthreads();
            const bool isRootA = (parent[t] == (unsigned)t);
            const bool isRootB = (parent[tb] == (unsigned)tb);
            {
                ull bc = bestComp[t];
                if (isRootA && bc != INF64) {
                    unsigned mn = (unsigned)((bc >> 10) & 0x3FFu), mx = (unsigned)(bc & 0x3FFu);
                    unsigned cm = comp[mn];
                    parent[t] = (cm == (unsigned)t) ? comp[mx] : cm;
                }
                bc = bestComp[tb];
                if (isRootB && bc != INF64) {
                    unsigned mn = (unsigned)((bc >> 10) & 0x3FFu), mx = (unsigned)(bc & 0x3FFu);
                    unsigned cm = comp[mn];
                    parent[tb] = (cm == (unsigned)tb) ? comp[mx] : cm;
                }
            }
            __syncthreads();
            {
                bool recA = false, recB = false;
                float dvalA = 0.0f, dvalB = 0.0f;
                unsigned p = parent[t];
                if (isRootA && p != (unsigned)t) {
                    unsigned gp = parent[p];
                    recA = !(gp == (unsigned)t) || ((unsigned)t < p);
                    if (recA) dvalA = sqrtf(__uint_as_float((unsigned)(bestComp[t] >> 20)) + 1e-12f);
                }
                p = parent[tb];
                if (isRootB && p != (unsigned)tb) {
                    unsigned gp = parent[p];
                    recB = !(gp == (unsigned)tb) || ((unsigned)tb < p);
                    if (recB) dvalB = sqrtf(__uint_as_float((unsigned)(bestComp[tb] >> 20)) + 1e-12f);
                }
                ull mA = __ballot(recA), mB = __ballot(recB);
                int cntA = __popcll(mA);
                int cnt = cntA + __popcll(mB);
                int base = 0;
                if ((t & 63) == 0 && cnt) base = atomicAdd(&deathCount, cnt);
                base = __shfl(base, 0, 64);
                ull below = (1ull << (t & 63)) - 1ull;
                if (recA) { int idx = base + __popcll(mA & below); if (idx < N - 1) deaths[idx] = dvalA; }
                if (recB) { int idx = base + cntA + __popcll(mB & below); if (idx < N - 1) deaths[idx] = dvalB; }
            }
            __syncthreads();
            {
                unsigned r = walk_root(parent, (unsigned)t);
                parent[t] = r;
                unsigned nc = walk_root(parent, comp[t]);
                comp[t] = nc; pts[t].w = __uint_as_float(nc); bestComp[t] = INF64;
                r = walk_root(parent, (unsigned)tb);
                parent[tb] = r;
                nc = walk_root(parent, comp[tb]);
                comp[tb] = nc; pts[tb].w = __uint_as_float(nc); bestComp[tb] = INF64;
            }
            __syncthreads();
            ++phase;
        }
    }

    // ================= Contracted Prim on remaining comps =================
    const int dcbase = deathCount;
    const int comps = N - dcbase;
    if (comps > 1) {
        unsigned* scomp = &pb[0][0];
        unsigned* hist = &pb[1][0];
        unsigned* wavemin = &pb[1][0];
        uint2* segs = (uint2*)&bestComp[0];
        const int lane = t & 63;
        const int wid = t >> 6;          // 0..7

        hist[t] = 0; hist[tb] = 0;
        __syncthreads();
        atomicAdd(&hist[comp[t]], 1u);
        atomicAdd(&hist[comp[tb]], 1u);
        __syncthreads();
        unsigned cA = hist[t], cB = hist[tb];
        unsigned incA = cA, incB = cB;
        #pragma unroll
        for (int d = 1; d < 64; d <<= 1) {
            unsigned uA = __shfl_up(incA, d, 64);
            unsigned uB = __shfl_up(incB, d, 64);
            if (lane >= d) { incA += uA; incB += uB; }
        }
        if (lane == 63) { wsum[wid] = incA; wsum[8 + wid] = incB; }
        __syncthreads();
        unsigned wofA = 0, totA = 0, wofB = 0;
        for (int i = 0; i < 8; ++i) {
            unsigned w = wsum[i];
            if (i < wid) wofA += w;
            totA += w;
        }
        for (int i = 0; i < wid; ++i) wofB += wsum[8 + i];
        unsigned exclA = wofA + incA - cA;               // bins 0..511
        unsigned exclB = totA + wofB + incB - cB;        // bins 512..1023
        if (cA) { segs[t].x = exclA; segs[t].y = exclA + cA; }
        if (cB) { segs[tb].x = exclB; segs[tb].y = exclB + cB; }
        __syncthreads();
        hist[t] = exclA; hist[tb] = exclB;
        __syncthreads();
        {
            unsigned pos = atomicAdd(&hist[comp[t]], 1u);
            spts[pos] = pts[t]; scomp[pos] = comp[t];
            pos = atomicAdd(&hist[comp[tb]], 1u);
            spts[pos] = pts[tb]; scomp[pos] = comp[tb];
        }
        __syncthreads();

        unsigned c_cur = comp[0];
        v2f pxv2 = (v2f){0.f, 0.f}, pyv2 = pxv2, pzv2 = pxv2;
        unsigned myc0 = 0, myc1 = 0, md0 = INF32, md1 = INF32;
        {
            float4 q0 = spts[t], q1 = spts[tb];
            myc0 = scomp[t];
            myc1 = scomp[tb];
            pxv2 = (v2f){q0.x, q1.x};
            pyv2 = (v2f){q0.y, q1.y};
            pzv2 = (v2f){q0.z, q1.z};
            if (myc0 == c_cur) pxv2.x = INFINITY;
            if (myc1 == c_cur) pxv2.y = INFINITY;
        }

        for (int step = 0; step < comps - 1; ++step) {
            {
                uint2 sg = segs[c_cur];
                const int jb = (int)sg.x, je = (int)sg.y, jl = je - 1;
                for (int base = jb; base < je; base += 4) {
                    float4 q0 = spts[base];
                    float4 q1 = spts[imin32(base + 1, jl)];
                    float4 q2 = spts[imin32(base + 2, jl)];
                    float4 q3 = spts[imin32(base + 3, jl)];
                    #define RELAX(qq)                                                        \
                        {                                                                    \
                            v2f dx = pxv2 - (v2f){qq.x, qq.x};                               \
                            v2f dy = pyv2 - (v2f){qq.y, qq.y};                               \
                            v2f dz = pzv2 - (v2f){qq.z, qq.z};                               \
                            v2f e = dx * dx;                                                 \
                            e = __builtin_elementwise_fma(dy, dy, e);                        \
                            e = __builtin_elementwise_fma(dz, dz, e);                        \
                            md0 = umin32(md0, (__float_as_uint(e.x) & 0xFFFFFC00u) | myc0);  \
                            md1 = umin32(md1, (__float_as_uint(e.y) & 0xFFFFFC00u) | myc1);  \
                        }
                    RELAX(q0) RELAX(q1) RELAX(q2) RELAX(q3)
                    #undef RELAX
                }
                unsigned v = umin32(md0, md1);
                DPP_MIN_SHR(v, 1);
                DPP_MIN_SHR(v, 2);
                DPP_MIN_SHR(v, 4);
                DPP_MIN_SHR(v, 8);
                unsigned r0 = (unsigned)__builtin_amdgcn_readlane((int)v, 15);
                unsigned r1 = (unsigned)__builtin_amdgcn_readlane((int)v, 31);
                unsigned r2 = (unsigned)__builtin_amdgcn_readlane((int)v, 47);
                unsigned r3 = (unsigned)__builtin_amdgcn_readlane((int)v, 63);
                if (lane == 0)
                    wavemin[(step & 1) * 8 + wid] = umin32(umin32(r0, r1), umin32(r2, r3));
            }
            __syncthreads();                     // 8-wave barrier
            {
                const uint4* wmv = (const uint4*)(wavemin + (step & 1) * 8);
                uint4 u0 = wmv[0], u1 = wmv[1];
                unsigned m0 = umin32(umin32(u0.x, u0.y), umin32(u0.z, u0.w));
                unsigned m1 = umin32(umin32(u1.x, u1.y), umin32(u1.z, u1.w));
                unsigned G = umin32(m0, m1);
                c_cur = G & 0x3FFu;
                if (t == 0)
                    deaths[dcbase + step] = sqrtf(__uint_as_float(G & 0xFFFFFC00u) + 1e-12f);
                if (myc0 == c_cur) { pxv2.x = INFINITY; md0 = INF32; }
                if (myc1 == c_cur) { pxv2.y = INFINITY; md1 = INF32; }
            }
        }
    }

    // ---- hybrid bitonic sort, 2 register elements/thread ----
    {
        float v0 = deaths[t], v1 = deaths[tb];
        if (t == TF - 1) v1 = INFINITY;          // element N-1 pad
        #pragma unroll
        for (int k = 2; k <= N; k <<= 1) {
            #pragma unroll
            for (int j = k >> 1; j > 0; j >>= 1) {
                const bool up0 = ((t & k) == 0);
                const bool up1 = ((tb & k) == 0);
                float u0, u1;
                if (j == 512) {
                    u0 = v1; u1 = v0;
                } else if (j >= 64) {
                    deaths[t] = v0; deaths[tb] = v1;
                    __syncthreads();
                    u0 = deaths[t ^ j];
                    u1 = deaths[tb ^ j];
                    __syncthreads();
                } else {
                    u0 = __shfl_xor(v0, j, 64);
                    u1 = __shfl_xor(v1, j, 64);
                }
                v0 = (((t & j) == 0) == up0) ? fminf(v0, u0) : fmaxf(v0, u0);
                v1 = (((tb & j) == 0) == up1) ? fminf(v1, u1) : fmaxf(v1, u1);
            }
        }
        float* dst = ws + (size_t)blk * N;
        dst[t] = v0;
        dst[tb] = (tb < N - 1) ? v1 : 0.0f;
    }
}

// Fused diff: 64 blocks; per-batch |a-b| sum -> atomicAdd into out (zeroed by final).
__global__ __launch_bounds__(256) void diff_kernel(const float* __restrict__ ws,
                                                   float* __restrict__ out) {
    __shared__ float red[4];
    const int t = threadIdx.x;
    const int b = blockIdx.x;
    const float* a = ws + (size_t)b * N;
    const float* c = ws + (size_t)(64 + b) * N;
    float sum = 0.0f;
    for (int i = t; i < N; i += 256)
        sum += fabsf(a[i] - c[i]);
    #pragma unroll
    for (int off = 32; off > 0; off >>= 1)
        sum += __shfl_down(sum, off, 64);
    if ((t & 63) == 0) red[t >> 6] = sum;
    __syncthreads();
    if (t == 0)
        atomicAdd(out, (red[0] + red[1] + red[2] + red[3]) * (1.0f / 64.0f));
}

extern "C" void kernel_launch(void* const* d_in, const int* in_sizes, int n_in,
                              void* d_out, int out_size, void* d_ws, size_t ws_size,
                              hipStream_t stream) {
    const float* gts = (const float*)d_in[0];
    const float* preds = (const float*)d_in[1];
    float* ws = (float*)d_ws;                     // sorted deaths live at ws[0 .. 128*N)
    unsigned* bests1 = (unsigned*)d_ws;           // 512 KiB (overwritten by sorted deaths)
    unsigned* bests2 = bests1 + 128 * N;          // 512 KiB
    const bool big = ws_size >= (size_t)(2u * 128u * N * 4u);

    if (big) {
        hipLaunchKernelGGL(scan1_kernel, dim3(256), dim3(T), 0, stream, gts, preds, bests1);
        hipLaunchKernelGGL(scan2_kernel, dim3(256), dim3(T), 0, stream, gts, preds, bests1, bests2);
        hipLaunchKernelGGL(final_kernel, dim3(128), dim3(TF), 0, stream,
                           gts, preds, ws, bests1, bests2, 2, (float*)d_out);
    } else {
        hipLaunchKernelGGL(final_kernel, dim3(128), dim3(TF), 0, stream,
                           gts, preds, ws, (const unsigned*)nullptr, (const unsigned*)nullptr, 0,
                           (float*)d_out);
    }
    hipLaunchKernelGGL(diff_kernel, dim3(64), dim3(256), 0, stream, ws, (float*)d_out);
}